// Round 9
// baseline (1724.599 us; speedup 1.0000x reference)
//
#include <hip/hip_runtime.h>

typedef __bf16 bf16;
typedef __bf16 bf16x8 __attribute__((ext_vector_type(8)));
typedef __bf16 bf16x4 __attribute__((ext_vector_type(4)));
typedef float f32x4 __attribute__((ext_vector_type(4)));

__device__ inline f32x4 mfma16(bf16x8 a, bf16x8 b, f32x4 c) {
    return __builtin_amdgcn_mfma_f32_16x16x32_bf16(a, b, c, 0, 0, 0);
}

// async global->LDS, 16B per lane. LDS dest is wave-uniform base + lane*16.
__device__ __forceinline__ void async_cp16(const void* g, void* l) {
    __builtin_amdgcn_global_load_lds(
        (__attribute__((address_space(1))) char*)g,
        (__attribute__((address_space(3))) char*)l,
        16, 0, 0);
}

// f32 -> bf16 weight conversion, vec4, grid-strided (2048 blocks).
__global__ __launch_bounds__(256) void w2b_kernel(const float* __restrict__ s,
                                                  bf16* __restrict__ d, int nvec4)
{
    for (size_t i = (size_t)blockIdx.x * 256 + threadIdx.x; i < (size_t)nvec4;
         i += (size_t)2048 * 256) {
        const float4 f = *(const float4*)(s + i * 4);
        bf16x4 t;
        t[0] = (bf16)f.x; t[1] = (bf16)f.y; t[2] = (bf16)f.z; t[3] = (bf16)f.w;
        *(bf16x4*)(d + i * 4) = t;
    }
}

// merged q/k/v weight conversion: q(4096 blk) -> dq, k(512) -> dq+4M, v(512) -> +4.5M
__global__ __launch_bounds__(256) void w2b_qkv_kernel(
    const float* __restrict__ qw, const float* __restrict__ kw,
    const float* __restrict__ vw, bf16* __restrict__ dq)
{
    int bid = blockIdx.x;
    const float* s; bf16* d;
    if (bid < 4096)      { s = qw; d = dq; }
    else if (bid < 4608) { s = kw; d = dq + 4194304; bid -= 4096; }
    else                 { s = vw; d = dq + 4718592; bid -= 4608; }
    const size_t i = ((size_t)bid * 256 + threadIdx.x) * 4;
    const float4 f = *(const float4*)(s + i);
    bf16x4 t;
    t[0] = (bf16)f.x; t[1] = (bf16)f.y; t[2] = (bf16)f.z; t[3] = (bf16)f.w;
    *(bf16x4*)(d + i) = t;
}

// merged gate/up weight conversion: gate(3584 blk) -> dg, up(3584) -> dg+3.5M
__global__ __launch_bounds__(256) void w2b_gu_kernel(
    const float* __restrict__ gw, const float* __restrict__ uw, bf16* __restrict__ dg)
{
    int bid = blockIdx.x;
    const float* s; bf16* d;
    if (bid < 3584) { s = gw; d = dg; }
    else            { s = uw; d = dg + 3670016; bid -= 3584; }
    const size_t i = ((size_t)bid * 256 + threadIdx.x) * 4;
    const float4 f = *(const float4*)(s + i);
    bf16x4 t;
    t[0] = (bf16)f.x; t[1] = (bf16)f.y; t[2] = (bf16)f.z; t[3] = (bf16)f.w;
    *(bf16x4*)(d + i) = t;
}

// ---------------------------------------------------------------------------
// 128x128-tile GEMM v3: BK=64, XOR swizzle, double-buffered prefetch (R7).
// C(MxN) = A(MxK)bf16 @ B(NxK)bf16^T, f32 accum. EPI1 adds residual.
// ---------------------------------------------------------------------------
template <int EPI>
__global__ __launch_bounds__(256) void gemm_kernel(
    const bf16* __restrict__ A, const bf16* __restrict__ B,
    const float* __restrict__ res, float* __restrict__ Cout,
    int M, int N, int K)
{
    __shared__ bf16 As[2][128][64];
    __shared__ bf16 Bs[2][128][64];
    const int tid = threadIdx.x;
    const int wave = tid >> 6, lane = tid & 63;
    const int quad = lane >> 4, l16 = lane & 15;
    const int xsw = l16 & 7;

    const int nby = M >> 7, nbx = N >> 7;
    const int nwg = nbx * nby;
    int bid = blockIdx.x;
    {
        const int q = nwg >> 3, r = nwg & 7;
        const int x = bid & 7, loc = bid >> 3;
        bid = (x < r ? x * (q + 1) : r * (q + 1) + (x - r) * q) + loc;
    }
    const int pg = nbx << 3;
    const int g = bid / pg, rem = bid - g * pg;
    const int by = (g << 3) + (rem & 7);
    const int bx = rem >> 3;
    const int row0 = by << 7, col0 = bx << 7;
    const int wrow = ((wave >> 1) << 6), wcol = ((wave & 1) << 6);

    f32x4 acc[4][4] = {};

    const int srow = tid >> 3;
    const int scol = ((tid & 7) ^ (srow & 7)) * 8;
    const bf16* Ag = A + (size_t)(row0 + srow) * K + scol;
    const bf16* Bg = B + (size_t)(col0 + srow) * K + scol;
    const size_t K32 = (size_t)32 * K;

#define STG128(BUF, KB) do { \
    _Pragma("unroll") for (int q = 0; q < 4; ++q) { \
        async_cp16(Ag + q * K32 + (KB), &As[BUF][0][0] + q * 2048 + wave * 512); \
        async_cp16(Bg + q * K32 + (KB), &Bs[BUF][0][0] + q * 2048 + wave * 512); } } while (0)

    const int NT = K >> 6;
    STG128(0, 0);
    __syncthreads();
    for (int t = 0; t < NT; ++t) {
        const int c = t & 1, n = c ^ 1;
        if (t + 1 < NT) STG128(n, (t + 1) * 64);   // in flight under this tile's compute
        bf16x8 af[8], bfr[8];
#pragma unroll
        for (int i = 0; i < 4; ++i) {
            af[i * 2 + 0] = *(const bf16x8*)(&As[c][wrow + i * 16 + l16][(quad ^ xsw) * 8]);
            af[i * 2 + 1] = *(const bf16x8*)(&As[c][wrow + i * 16 + l16][((4 + quad) ^ xsw) * 8]);
        }
#pragma unroll
        for (int j = 0; j < 4; ++j) {
            bfr[j * 2 + 0] = *(const bf16x8*)(&Bs[c][wcol + j * 16 + l16][(quad ^ xsw) * 8]);
            bfr[j * 2 + 1] = *(const bf16x8*)(&Bs[c][wcol + j * 16 + l16][((4 + quad) ^ xsw) * 8]);
        }
#pragma unroll
        for (int i = 0; i < 4; ++i)
#pragma unroll
            for (int j = 0; j < 4; ++j) {
                acc[i][j] = mfma16(af[i * 2 + 0], bfr[j * 2 + 0], acc[i][j]);
                acc[i][j] = mfma16(af[i * 2 + 1], bfr[j * 2 + 1], acc[i][j]);
            }
        __syncthreads();   // drains prefetch (residual latency only) + barrier
    }
#undef STG128

#pragma unroll
    for (int i = 0; i < 4; ++i) {
        const int row = row0 + wrow + i * 16 + quad * 4;
#pragma unroll
        for (int j = 0; j < 4; ++j) {
            const int col = col0 + wcol + j * 16 + l16;
#pragma unroll
            for (int r = 0; r < 4; ++r) {
                const size_t idx = (size_t)(row + r) * N + col;
                float v = acc[i][j][r];
                if (EPI == 1) Cout[idx] = v + res[idx];
                else          Cout[idx] = v;
            }
        }
    }
}

// ---------------------------------------------------------------------------
// 256x256-tile GEMM, v3: 2-barrier counted-pipeline per K-tile (see R4 notes).
// EPI: 0 = f32 out; 1 = f32 out + residual; 2 = hout = bf16(silu(res)*acc)
// ---------------------------------------------------------------------------
template <int EPI>
__global__ __launch_bounds__(512, 2) void gemm256_kernel(
    const bf16* __restrict__ A, const bf16* __restrict__ B,
    const float* __restrict__ res, float* __restrict__ Cout,
    bf16* __restrict__ hout, int M, int N, int K)
{
    __shared__ bf16 As[2][2][128][64];
    __shared__ bf16 Bs[2][2][128][64];
    const int tid = threadIdx.x;
    const int wid = tid >> 6, lane = tid & 63;
    const int quad = lane >> 4, l16 = lane & 15;
    const int wm = wid >> 2, wn = wid & 3;
    const int xsw = l16 & 7;
    const int bofs = (wn & 1) * 64;

    const int nby = M >> 8, nbx = N >> 8;
    const int nwg = nbx * nby;
    int bid = blockIdx.x;
    {
        const int q = nwg >> 3, r = nwg & 7;
        const int x = bid & 7, loc = bid >> 3;
        bid = (x < r ? x * (q + 1) : r * (q + 1) + (x - r) * q) + loc;
    }
    const int pg = nbx << 3;
    const int g = bid / pg, rem = bid - g * pg;
    const int by = (g << 3) + (rem & 7);
    const int bx = rem >> 3;
    const int row0 = by << 8, col0 = bx << 8;

    const int srow = tid >> 3;
    const int scol = ((tid & 7) ^ ((tid >> 3) & 7)) * 8;
    const bf16* Abase = A + (size_t)(row0 + srow) * K + scol;
    const bf16* Bbase = B + (size_t)(col0 + srow) * K + scol;
    const size_t K64 = (size_t)K * 64;
    const size_t K128 = (size_t)K * 128;

    f32x4 acc[8][4] = {};
    bf16x8 af[8], bf0[4], bf1[4];

#define STG_A(BUF, HH, KB) do { \
    const bf16* _g = Abase + (size_t)(HH) * K128 + (KB); \
    bf16* _l = &As[BUF][HH][0][0] + wid * 512; \
    async_cp16(_g, _l); \
    async_cp16(_g + K64, _l + 4096); } while (0)
#define STG_B(BUF, HH, KB) do { \
    const bf16* _g = Bbase + (size_t)(HH) * K128 + (KB); \
    bf16* _l = &Bs[BUF][HH][0][0] + wid * 512; \
    async_cp16(_g, _l); \
    async_cp16(_g + K64, _l + 4096); } while (0)

#define RD_A(BUF, RH) do { \
    const bf16 (*Ah_)[64] = As[BUF][wm]; \
    _Pragma("unroll") for (int f = 0; f < 4; ++f) { \
        af[f*2+0] = *(const bf16x8*)(&Ah_[(RH)*64 + f*16 + l16][(quad ^ xsw) * 8]); \
        af[f*2+1] = *(const bf16x8*)(&Ah_[(RH)*64 + f*16 + l16][((4 + quad) ^ xsw) * 8]); } } while (0)

#define RD_B(BUF, CH, BF) do { \
    const bf16 (*Bh_)[64] = Bs[BUF][wn >> 1]; \
    _Pragma("unroll") for (int f = 0; f < 2; ++f) { \
        BF[f*2+0] = *(const bf16x8*)(&Bh_[bofs + (CH)*32 + f*16 + l16][(quad ^ xsw) * 8]); \
        BF[f*2+1] = *(const bf16x8*)(&Bh_[bofs + (CH)*32 + f*16 + l16][((4 + quad) ^ xsw) * 8]); } } while (0)

#define MFMA_Q(RH, CH, BF) do { \
    _Pragma("unroll") for (int f = 0; f < 4; ++f) \
    _Pragma("unroll") for (int f2 = 0; f2 < 2; ++f2) { \
        acc[(RH)*4+f][(CH)*2+f2] = mfma16(af[f*2+0], BF[f2*2+0], acc[(RH)*4+f][(CH)*2+f2]); \
        acc[(RH)*4+f][(CH)*2+f2] = mfma16(af[f*2+1], BF[f2*2+1], acc[(RH)*4+f][(CH)*2+f2]); } } while (0)

    const int NT = K >> 6;
    STG_A(0, 0, 0); STG_A(0, 1, 0); STG_B(0, 0, 0); STG_B(0, 1, 0);
    if (NT > 1) {
        STG_A(1, 0, 64); STG_A(1, 1, 64); STG_B(1, 0, 64); STG_B(1, 1, 64);
        asm volatile("s_waitcnt vmcnt(8)" ::: "memory");
    } else {
        asm volatile("s_waitcnt vmcnt(0)" ::: "memory");
    }
    __builtin_amdgcn_sched_barrier(0);
    __builtin_amdgcn_s_barrier();
    RD_A(0, 0); RD_B(0, 0, bf0); RD_B(0, 1, bf1);
    __builtin_amdgcn_sched_barrier(0);

    for (int t = 0; t < NT; ++t) {
        const int c = t & 1, n = c ^ 1;
        const int kb1 = (t + 1) << 6, kb2 = (t + 2) << 6;
        // ---------------- phase A ----------------
        if (t >= 1 && t + 1 < NT) { STG_A(n, 0, kb1); STG_A(n, 1, kb1); }
        asm volatile("s_waitcnt lgkmcnt(4)" ::: "memory");   // af0+bf0 ready
        __builtin_amdgcn_sched_barrier(0);
        __builtin_amdgcn_s_setprio(1);
        MFMA_Q(0, 0, bf0);
        __builtin_amdgcn_s_setprio(0);
        asm volatile("s_waitcnt lgkmcnt(0)" ::: "memory");   // bf1 ready
        __builtin_amdgcn_sched_barrier(0);
        __builtin_amdgcn_s_setprio(1);
        MFMA_Q(0, 1, bf1);
        __builtin_amdgcn_s_setprio(0);
        RD_A(c, 1);                                          // af1: hides under Q01 drain
        __builtin_amdgcn_sched_barrier(0);
        __builtin_amdgcn_s_barrier();                        // BAR1
        // ---------------- phase B ----------------
        if (t + 2 < NT) { STG_B(c, 0, kb2); STG_B(c, 1, kb2); }
        asm volatile("s_waitcnt lgkmcnt(0)" ::: "memory");   // af1 ready
        __builtin_amdgcn_sched_barrier(0);
        __builtin_amdgcn_s_setprio(1);
        MFMA_Q(1, 0, bf0);
        MFMA_Q(1, 1, bf1);
        __builtin_amdgcn_s_setprio(0);
        if (t + 1 < NT) {
            if (t + 2 < NT) { asm volatile("s_waitcnt vmcnt(4)" ::: "memory"); }
            else            { asm volatile("s_waitcnt vmcnt(0)" ::: "memory"); }
            __builtin_amdgcn_sched_barrier(0);
            RD_A(n, 0); RD_B(n, 0, bf0); RD_B(n, 1, bf1);    // next tile's operands
            __builtin_amdgcn_sched_barrier(0);
        }
        __builtin_amdgcn_s_barrier();                        // BAR2
    }
#undef STG_A
#undef STG_B
#undef RD_A
#undef RD_B
#undef MFMA_Q

#pragma unroll
    for (int fr = 0; fr < 8; ++fr) {
        const int row = row0 + wm * 128 + fr * 16 + quad * 4;
#pragma unroll
        for (int fc = 0; fc < 4; ++fc) {
            const int col = col0 + wn * 64 + fc * 16 + l16;
#pragma unroll
            for (int r = 0; r < 4; ++r) {
                const size_t idx = (size_t)(row + r) * N + col;
                float v = acc[fr][fc][r];
                if (EPI == 1) {
                    Cout[idx] = v + res[idx];
                } else if (EPI == 2) {
                    const float gg = res[idx];
                    hout[idx] = (bf16)(gg * (1.f / (1.f + __expf(-gg))) * v);
                } else {
                    Cout[idx] = v;
                }
            }
        }
    }
}

// ---------------------------------------------------------------------------
// prenorm+concat: xcat[row,0:1024]=rmsnorm(emb), [1024:2048]=rmsnorm(hid)
// ---------------------------------------------------------------------------
__global__ __launch_bounds__(256) void prenorm_kernel(
    const float* __restrict__ emb, const float* __restrict__ hid,
    const float* __restrict__ we, const float* __restrict__ wh,
    bf16* __restrict__ xcat)
{
    const int rr = blockIdx.x * 4 + (threadIdx.x >> 6);
    const int lane = threadIdx.x & 63;
    const int half = rr & 1, row = rr >> 1;
    const float* x = (half ? hid : emb) + (size_t)row * 1024;
    const float* w = half ? wh : we;
    float4 v[4]; float ss = 0.f;
#pragma unroll
    for (int j = 0; j < 4; ++j) {
        v[j] = *(const float4*)(x + (size_t)(lane + 64 * j) * 4);
        ss += v[j].x * v[j].x + v[j].y * v[j].y + v[j].z * v[j].z + v[j].w * v[j].w;
    }
#pragma unroll
    for (int m = 32; m; m >>= 1) ss += __shfl_xor(ss, m, 64);
    const float rms = rsqrtf(ss * (1.f / 1024.f) + 1e-6f);
    bf16* o = xcat + (size_t)row * 2048 + half * 1024;
#pragma unroll
    for (int j = 0; j < 4; ++j) {
        const int d = (lane + 64 * j) * 4;
        float4 wv = *(const float4*)(w + d);
        bf16x4 t;
        t[0] = (bf16)(v[j].x * rms * wv.x);
        t[1] = (bf16)(v[j].y * rms * wv.y);
        t[2] = (bf16)(v[j].z * rms * wv.z);
        t[3] = (bf16)(v[j].w * rms * wv.w);
        *(bf16x4*)(o + d) = t;
    }
}

// rmsnorm over H=1024, f32 in -> bf16 out, one wave per row
__global__ __launch_bounds__(256) void rmsnorm_kernel(
    const float* __restrict__ xin, const float* __restrict__ w, bf16* __restrict__ out)
{
    const int row = blockIdx.x * 4 + (threadIdx.x >> 6);
    const int lane = threadIdx.x & 63;
    const float* x = xin + (size_t)row * 1024;
    float4 v[4]; float ss = 0.f;
#pragma unroll
    for (int j = 0; j < 4; ++j) {
        v[j] = *(const float4*)(x + (size_t)(lane + 64 * j) * 4);
        ss += v[j].x * v[j].x + v[j].y * v[j].y + v[j].z * v[j].z + v[j].w * v[j].w;
    }
#pragma unroll
    for (int m = 32; m; m >>= 1) ss += __shfl_xor(ss, m, 64);
    const float rms = rsqrtf(ss * (1.f / 1024.f) + 1e-6f);
    bf16* o = out + (size_t)row * 1024;
#pragma unroll
    for (int j = 0; j < 4; ++j) {
        const int d = (lane + 64 * j) * 4;
        float4 wv = *(const float4*)(w + d);
        bf16x4 t;
        t[0] = (bf16)(v[j].x * rms * wv.x);
        t[1] = (bf16)(v[j].y * rms * wv.y);
        t[2] = (bf16)(v[j].z * rms * wv.z);
        t[3] = (bf16)(v[j].w * rms * wv.w);
        *(bf16x4*)(o + d) = t;
    }
}

// ---------------------------------------------------------------------------
// q prep, vectorized: one float4 per lane (d = 4*lane..4*lane+3).
// ---------------------------------------------------------------------------
__global__ __launch_bounds__(256) void qprep_kernel(
    const float* __restrict__ qg, const float* __restrict__ qn_w, bf16* __restrict__ qa)
{
    const int row = blockIdx.x * 4 + (threadIdx.x >> 6);  // (b*L+l)*8+h
    const int lane = threadIdx.x & 63;
    const int h = row & 7, bl = row >> 3;
    const int l = bl & 2047, b = bl >> 11;
    const float* x = qg + (size_t)row * 512;
    float4 v = *(const float4*)(x + lane * 4);
    float ss = v.x * v.x + v.y * v.y + v.z * v.z + v.w * v.w;
#pragma unroll
    for (int m = 32; m; m >>= 1) ss += __shfl_xor(ss, m, 64);
    const float rms = rsqrtf(ss * (1.f / 256.f) + 1e-6f);
    const float4 wv = *(const float4*)(qn_w + lane * 4);
    float y0 = v.x * rms * wv.x, y1 = v.y * rms * wv.y;
    float y2 = v.z * rms * wv.z, y3 = v.w * rms * wv.w;
    if (lane < 16) {
        const float inv0 = powf(1e7f, -(float)(4 * lane) * (1.f / 64.f));
        const float inv1 = powf(1e7f, -(float)(4 * lane + 2) * (1.f / 64.f));
        const float a0 = (float)l * inv0, a1 = (float)l * inv1;
        const float c0 = cosf(a0), s0 = sinf(a0), c1 = cosf(a1), s1 = sinf(a1);
        const float r0 = y0 * c0 - y1 * s0, r1 = y0 * s0 + y1 * c0;
        const float r2 = y2 * c1 - y3 * s1, r3 = y2 * s1 + y3 * c1;
        y0 = r0; y1 = r1; y2 = r2; y3 = r3;
    }
    bf16* o = qa + ((size_t)((b * 8 + h) * 2048 + l)) * 256 + lane * 4;
    bf16x4 t;
    t[0] = (bf16)(y0 * 0.0625f); t[1] = (bf16)(y1 * 0.0625f);
    t[2] = (bf16)(y2 * 0.0625f); t[3] = (bf16)(y3 * 0.0625f);
    *(bf16x4*)o = t;
}

// k prep, vectorized: same minus scale; kvf rows 1024 wide (merged k|v out).
__global__ __launch_bounds__(256) void kprep_kernel(
    const float* __restrict__ kvf, const float* __restrict__ kn_w, bf16* __restrict__ ka)
{
    const int row = blockIdx.x * 4 + (threadIdx.x >> 6);  // (b*L+l)*2+kv
    const int lane = threadIdx.x & 63;
    const int kv = row & 1, bl = row >> 1;
    const int l = bl & 2047, b = bl >> 11;
    const float* x = kvf + (size_t)bl * 1024 + kv * 256;
    float4 v = *(const float4*)(x + lane * 4);
    float ss = v.x * v.x + v.y * v.y + v.z * v.z + v.w * v.w;
#pragma unroll
    for (int m = 32; m; m >>= 1) ss += __shfl_xor(ss, m, 64);
    const float rms = rsqrtf(ss * (1.f / 256.f) + 1e-6f);
    const float4 wv = *(const float4*)(kn_w + lane * 4);
    float y0 = v.x * rms * wv.x, y1 = v.y * rms * wv.y;
    float y2 = v.z * rms * wv.z, y3 = v.w * rms * wv.w;
    if (lane < 16) {
        const float inv0 = powf(1e7f, -(float)(4 * lane) * (1.f / 64.f));
        const float inv1 = powf(1e7f, -(float)(4 * lane + 2) * (1.f / 64.f));
        const float a0 = (float)l * inv0, a1 = (float)l * inv1;
        const float c0 = cosf(a0), s0 = sinf(a0), c1 = cosf(a1), s1 = sinf(a1);
        const float r0 = y0 * c0 - y1 * s0, r1 = y0 * s0 + y1 * c0;
        const float r2 = y2 * c1 - y3 * s1, r3 = y2 * s1 + y3 * c1;
        y0 = r0; y1 = r1; y2 = r2; y3 = r3;
    }
    bf16* o = ka + ((size_t)((b * 2 + kv) * 2048 + l)) * 256 + lane * 4;
    bf16x4 t;
    t[0] = (bf16)y0; t[1] = (bf16)y1; t[2] = (bf16)y2; t[3] = (bf16)y3;
    *(bf16x4*)o = t;
}

// v prep: merged-layout (rows 1024 wide, v at col 512+kv*256+d)
// -> (B,NKV,D,L) bf16 via LDS 64x64 tile transpose.
__global__ __launch_bounds__(256) void vprep_kernel(const float* __restrict__ kvf,
                                                    bf16* __restrict__ vt)
{
    __shared__ float t[64][65];
    const int l0 = blockIdx.x << 6;
    const int d0 = blockIdx.y << 6;
    const int b = blockIdx.z >> 1, kv = blockIdx.z & 1;
    const int tx = threadIdx.x & 63, ty = threadIdx.x >> 6;
    const float* src = kvf + (size_t)b * 2048 * 1024 + 512 + kv * 256;
#pragma unroll
    for (int j = 0; j < 16; ++j) {
        const int l = ty + j * 4;
        t[l][tx] = src[(size_t)(l0 + l) * 1024 + d0 + tx];
    }
    __syncthreads();
    bf16* dst = vt + (size_t)(b * 2 + kv) * 256 * 2048;
#pragma unroll
    for (int j = 0; j < 16; ++j) {
        const int d = ty + j * 4;
        dst[(size_t)(d0 + d) * 2048 + l0 + tx] = (bf16)t[tx][d];
    }
}

// ---------------------------------------------------------------------------
// flash attention v4: balanced pairing + fused gating + double-buffered
// global_load_lds K/V staging + ONE barrier per kv-tile.
//  - K staged with pre-swizzled GLOBAL source (XOR involution), linear LDS
//    dest (rule #21 pattern); read-side XOR unchanged from verified R8 form.
//  - Pw is per-wave: no block barrier, just lgkmcnt(0) between write & read.
//  - Tile-end: vmcnt(0) (next buffer landed; issued a full tile ago) +
//    s_barrier (all readers of current buffer done -> safe to overwrite at
//    t+2's staging, which follows t+1's end barrier).
// LDS 68 KiB -> still 2 blocks/CU (grid 512 is the binding limit anyway).
// ---------------------------------------------------------------------------
__global__ __launch_bounds__(256) void attn_kernel(
    const bf16* __restrict__ qa, const bf16* __restrict__ ka,
    const bf16* __restrict__ vt, const float* __restrict__ qg,
    bf16* __restrict__ ag)
{
    __shared__ bf16 Ks[2][32 * 256];
    __shared__ bf16 Vt[2][256 * 32];
    __shared__ bf16 Pw[4 * 16 * 32];
    const int tid = threadIdx.x;
    const int wave = tid >> 6, lane = tid & 63;
    const int quad = lane >> 4, l16 = lane & 15;
    const int bid = blockIdx.x;
    const int j = bid & 15, h = (bid >> 4) & 7, b = bid >> 7;
    const int kvh = h >> 2;
    const bf16* qptr = qa + ((size_t)(b * 8 + h)) * 2048 * 256;
    const bf16* kptr = ka + ((size_t)(b * 2 + kvh)) * 2048 * 256;
    const bf16* vptr = vt + ((size_t)(b * 2 + kvh)) * 256 * 2048;

    // staging: call c covers idx = c*256 + tid; LDS dest linear (idx*16B),
    // K global col pre-swizzled by row (involution with the read-side XOR).
#define STAGE_KV(BUF, KVS) do { \
    _Pragma("unroll") for (int c = 0; c < 4; ++c) { \
        const int idx = c * 256 + tid; \
        const int kr = idx >> 5; \
        const int kcs = ((idx & 31) ^ (kr & 7)) * 8; \
        async_cp16(kptr + (size_t)((KVS) + kr) * 256 + kcs, \
                   &Ks[BUF][0] + c * 2048 + wave * 512); \
        const int vd = idx >> 2, vc = (idx & 3) * 8; \
        async_cp16(vptr + (size_t)vd * 2048 + (KVS) + vc, \
                   &Vt[BUF][0] + c * 2048 + wave * 512); } } while (0)

    for (int s = 0; s < 2; ++s) {
        const int qt = s ? (31 - j) : j;
        const int qbase = qt * 64 + wave * 16;

        bf16x8 qf[8];
#pragma unroll
        for (int db = 0; db < 8; ++db)
            qf[db] = *(const bf16x8*)(qptr + (size_t)(qbase + l16) * 256 + db * 32 + quad * 8);

        f32x4 o_acc[16] = {};
        float m_i[4], l_i[4];
#pragma unroll
        for (int r = 0; r < 4; ++r) { m_i[r] = -1e30f; l_i[r] = 0.f; }

        const int ntiles = qt * 2 + 2;
        STAGE_KV(0, 0);
        asm volatile("s_waitcnt vmcnt(0)" ::: "memory");
        __builtin_amdgcn_s_barrier();
        __builtin_amdgcn_sched_barrier(0);

        for (int kt = 0; kt < ntiles; ++kt) {
            const int cb = kt & 1, nb = cb ^ 1;
            const int kvs = kt * 32;
            if (kt + 1 < ntiles) STAGE_KV(nb, kvs + 32);   // async, lands by tile end

            f32x4 s0 = {}, s1 = {};
#pragma unroll
            for (int db = 0; db < 8; ++db) {
                const int ch = (db * 4 + quad) ^ (l16 & 7);   // (16+l16)&7 == l16&7
                bf16x8 k0 = *(const bf16x8*)(&Ks[cb][l16 * 256 + ch * 8]);
                bf16x8 k1 = *(const bf16x8*)(&Ks[cb][(16 + l16) * 256 + ch * 8]);
                s0 = mfma16(qf[db], k0, s0);
                s1 = mfma16(qf[db], k1, s1);
            }

            float alpha[4], p0v[4], p1v[4];
#pragma unroll
            for (int r = 0; r < 4; ++r) {
                const int qrow = qbase + quad * 4 + r;
                float a0 = (kvs + l16 > qrow) ? -1e30f : s0[r];
                float a1 = (kvs + 16 + l16 > qrow) ? -1e30f : s1[r];
                float mx = fmaxf(a0, a1);
#pragma unroll
                for (int m = 8; m; m >>= 1) mx = fmaxf(mx, __shfl_xor(mx, m, 64));
                const float mnew = fmaxf(m_i[r], mx);
                const float a = __expf(m_i[r] - mnew);
                const float p0 = __expf(a0 - mnew);
                const float p1 = __expf(a1 - mnew);
                float ps = p0 + p1;
#pragma unroll
                for (int m = 8; m; m >>= 1) ps += __shfl_xor(ps, m, 64);
                l_i[r] = l_i[r] * a + ps;
                m_i[r] = mnew;
                alpha[r] = a; p0v[r] = p0; p1v[r] = p1;
            }
#pragma unroll
            for (int t = 0; t < 16; ++t) {
                f32x4 o = o_acc[t];
                o[0] *= alpha[0]; o[1] *= alpha[1]; o[2] *= alpha[2]; o[3] *= alpha[3];
                o_acc[t] = o;
            }
            // Pw is per-wave: lgkmcnt(0) guarantees the ds_writes completed
            // before the cross-lane ds_read below (no block barrier needed).
            bf16* pw = &Pw[wave * 16 * 32];
#pragma unroll
            for (int r = 0; r < 4; ++r) {
                pw[(quad * 4 + r) * 32 + l16]      = (bf16)p0v[r];
                pw[(quad * 4 + r) * 32 + 16 + l16] = (bf16)p1v[r];
            }
            asm volatile("s_waitcnt lgkmcnt(0)" ::: "memory");
            __builtin_amdgcn_sched_barrier(0);
            const bf16x8 pa = *(const bf16x8*)(&pw[l16 * 32 + quad * 8]);
#pragma unroll
            for (int t = 0; t < 16; ++t) {
                bf16x8 vfr = *(const bf16x8*)(&Vt[cb][(t * 16 + l16) * 32 + quad * 8]);
                o_acc[t] = mfma16(pa, vfr, o_acc[t]);
            }
            // single end-of-tile sync: staged buffer landed + readers done
            asm volatile("s_waitcnt vmcnt(0)" ::: "memory");
            __builtin_amdgcn_s_barrier();
            __builtin_amdgcn_sched_barrier(0);
        }

        // fused gating epilogue: ag[(b,row,h*256+d)] = bf16(o * sigmoid(gate))
#pragma unroll
        for (int r = 0; r < 4; ++r) {
            const float inv = 1.f / l_i[r];
            const int row = qbase + quad * 4 + r;
            const float* gr = qg + ((size_t)((b * 2048 + row) * 8 + h)) * 512 + 256;
            bf16* ar = ag + ((size_t)(b * 2048 + row)) * 2048 + h * 256;
#pragma unroll
            for (int t = 0; t < 16; ++t) {
                const int d = t * 16 + l16;
                const float o = o_acc[t][r] * inv;
                const float gg = gr[d];
                ar[d] = (bf16)(o * (1.f / (1.f + __expf(-gg))));
            }
        }
        // s=1 prologue staging is safe: all waves passed the final tile's
        // end barrier of s=0; only global ops occur in between.
    }
#undef STAGE_KV
}

// ---------------------------------------------------------------------------
extern "C" void kernel_launch(void* const* d_in, const int* in_sizes, int n_in,
                              void* d_out, int out_size, void* d_ws, size_t ws_size,
                              hipStream_t stream)
{
    const float* emb       = (const float*)d_in[0];
    const float* hid       = (const float*)d_in[1];
    const float* pre_emb_w = (const float*)d_in[2];
    const float* pre_hid_w = (const float*)d_in[3];
    const float* fc_w      = (const float*)d_in[4];
    const float* in_ln_w   = (const float*)d_in[5];
    const float* q_w       = (const float*)d_in[6];
    const float* k_w       = (const float*)d_in[7];
    const float* v_w       = (const float*)d_in[8];
    const float* o_w       = (const float*)d_in[9];
    const float* qn_w      = (const float*)d_in[10];
    const float* kn_w      = (const float*)d_in[11];
    const float* post_ln_w = (const float*)d_in[12];
    const float* gate_w    = (const float*)d_in[13];
    const float* up_w      = (const float*)d_in[14];
    const float* down_w    = (const float*)d_in[15];
    const float* norm_w    = (const float*)d_in[16];
    const float* lm_w      = (const float*)d_in[17];
    float* out = (float*)d_out;
    char* ws = (char*)d_ws;

    // workspace layout (lifetime-overlapped), total 360 MiB (unchanged)
    float* xres = (float*)(ws + 0);                 // 32 MiB, residual (in-place)
    bf16*  xln  = (bf16*)(ws + 33554432);           // 16 MiB, reused 3x
    char*  C    = ws + 50331648;                    // 128 MiB: qg then gf (+ wb slots)
    char*  D    = ws + 184549376;                   // 128 MiB: xcat/kvf then ag
    char*  E    = ws + 318767104;                   // 56 MiB: qa/ka/va then hb
    float* qg   = (float*)C;
    float* gf   = (float*)C;
    bf16*  xcat = (bf16*)D;
    float* kvf  = (float*)(D + 33554432);    // 32 MiB merged k|v GEMM out (8192x1024)
    bf16*  ag   = (bf16*)(D + 67108864);     // 32 MiB
    bf16*  qa   = (bf16*)E;
    bf16*  ka   = (bf16*)(E + 33554432);
    bf16*  va   = (bf16*)(E + 41943040);
    bf16*  hb   = (bf16*)E;                  // 56 MiB, written after qa/ka/va dead
    // bf16 weight scratch slots (placed in regions dead at time of use)
    bf16*  wbC  = (bf16*)C;                  // fc(4M), o(4M), down(7M), lm(32M)
    bf16*  wbD  = (bf16*)D;                  // q(8M) + k(1M) + v(1M) @ D+0..10M
    bf16*  wkv  = (bf16*)D + 4194304;        // k|v rows (1024x1024 bf16)
    bf16*  wbDt = (bf16*)(D + 117440512);    // gate(7M) + up(7M)

    prenorm_kernel<<<4096, 256, 0, stream>>>(emb, hid, pre_emb_w, pre_hid_w, xcat);

    w2b_kernel<<<2048, 256, 0, stream>>>(fc_w, wbC, 524288);               // 1024x2048
    gemm_kernel<0><<<512, 256, 0, stream>>>(xcat, wbC, nullptr, xres, 8192, 1024, 2048);
    rmsnorm_kernel<<<2048, 256, 0, stream>>>(xres, in_ln_w, xln);

    w2b_qkv_kernel<<<5120, 256, 0, stream>>>(q_w, k_w, v_w, wbD);
    gemm256_kernel<0><<<512, 512, 0, stream>>>(xln, wbD, nullptr, qg, nullptr, 8192, 4096, 1024);
    gemm_kernel<0><<<512, 256, 0, stream>>>(xln, wkv, nullptr, kvf, 8192, 1024, 1024);  // merged k|v

    qprep_kernel<<<16384, 256, 0, stream>>>(qg, qn_w, qa);
    kprep_kernel<<<4096, 256, 0, stream>>>(kvf, kn_w, ka);
    vprep_kernel<<<dim3(32, 4, 8), 256, 0, stream>>>(kvf, va);
    attn_kernel<<<512, 256, 0, stream>>>(qa, ka, va, qg, ag);   // fused gating

    w2b_kernel<<<2048, 256, 0, stream>>>(o_w, wbC, 524288);                // 1024x2048
    gemm_kernel<1><<<512, 256, 0, stream>>>(ag, wbC, xres, xres, 8192, 1024, 2048);
    rmsnorm_kernel<<<2048, 256, 0, stream>>>(xres, post_ln_w, xln);

    w2b_gu_kernel<<<7168, 256, 0, stream>>>(gate_w, up_w, wbDt);
    gemm256_kernel<0><<<448, 512, 0, stream>>>(xln, wbDt, nullptr, gf, nullptr, 8192, 3584, 1024);
    gemm256_kernel<2><<<448, 512, 0, stream>>>(xln, wbDt + 3670016, gf, nullptr, hb, 8192, 3584, 1024);

    w2b_kernel<<<2048, 256, 0, stream>>>(down_w, wbC, 917504);             // 1024x3584
    gemm_kernel<1><<<512, 256, 0, stream>>>(hb, wbC, xres, xres, 8192, 1024, 3584);
    rmsnorm_kernel<<<2048, 256, 0, stream>>>(xres, norm_w, xln);

    w2b_kernel<<<2048, 256, 0, stream>>>(lm_w, wbC, 4194304);              // 16384x1024
    gemm256_kernel<0><<<2048, 512, 0, stream>>>(xln, wbC, nullptr, out, nullptr, 8192, 16384, 1024);
}